// Round 7
// baseline (865.684 us; speedup 1.0000x reference)
//
#include <hip/hip_runtime.h>
#include <hip/hip_bf16.h>

typedef __hip_bfloat16 bf16;
using bf16x8 = __attribute__((ext_vector_type(8))) short;   // MFMA A/B frag (4 VGPR)
using f32x4  = __attribute__((ext_vector_type(4))) float;   // MFMA C/D frag

#define Bn 4
#define Dm 512
#define Hh 8
#define V3 3
#define Lq 1024
#define NM (Bn*Hh*V3)   // 96 attention maps

#define WPITCH 144      // bf16 LDS row pitch in BYTES: 16B-aligned, bank-skewed

__device__ __forceinline__ unsigned short f2bf(float x) {
    bf16 h = __float2bfloat16(x);
    return *reinterpret_cast<unsigned short*>(&h);
}
__device__ __forceinline__ float bfbits2f(unsigned short u) {
    return __uint_as_float((unsigned)u << 16);
}

constexpr float SCALE = 0.57735026919f; // 1/sqrt(3)

// ---------------------------------------------------------------------------
// Kernel 1: ALL THREE projections via MFMA (split-bf16 3-term compensation).
// (unchanged from R6)
// ---------------------------------------------------------------------------
__global__ __launch_bounds__(256, 4) void proj_all_kernel(
    const float* __restrict__ xq, const float* __restrict__ xk,
    const float* __restrict__ xv,
    const float* __restrict__ Wq, const float* __restrict__ Wk,
    const float* __restrict__ Wv,
    unsigned short* __restrict__ Qh, unsigned short* __restrict__ Ql,
    unsigned short* __restrict__ Kh, unsigned short* __restrict__ Kl,
    unsigned short* __restrict__ Vt)
{
    __shared__ unsigned char Wlds[2 * 64 * WPITCH];   // Wh | Wl, 18432 B
    unsigned char* LWh = Wlds;
    unsigned char* LWl = Wlds + 64 * WPITCH;

    const int fid = (blockIdx.z * gridDim.y + blockIdx.y) * gridDim.x + blockIdx.x;
    const int nid = (fid & 7) * 576 + (fid >> 3);
    const int x_  = nid & 15;          // l-block (16)
    const int y_  = (nid >> 4) & 7;    // e-block (8) == head
    const int zz  = nid >> 7;          // 0..35
    const int pid = zz / 12;           // 0=Q 1=K 2=V
    const int pl  = zz % 12;
    const int b   = pl / V3;
    const int v   = pl % V3;

    const float* xsrc = (pid == 0) ? xq : (pid == 1) ? xk : xv;
    const float* W    = (pid == 0) ? Wq : (pid == 1) ? Wk : Wv;

    const int l0 = x_ * 64;
    const int e0 = y_ * 64;
    const int m  = (b * Hh + y_) * V3 + v;

    const int tid  = threadIdx.x;
    const int w    = tid >> 6;
    const int ln   = tid & 63;
    const int ln15 = ln & 15;
    const int lq   = ln >> 4;
    const int wl   = w * 16 + ln15;    // this lane's block-local l

    const float* xbase = xsrc + (size_t)b * Dm * V3 * Lq + (size_t)v * Lq + l0 + wl;

    f32x4 acc[4];
    #pragma unroll
    for (int i = 0; i < 4; ++i) acc[i] = (f32x4)0.f;

    for (int ph = 0; ph < 8; ++ph) {
        const int d0 = ph * 64;

        float xraw[16];
        #pragma unroll
        for (int kq = 0; kq < 2; ++kq)
            #pragma unroll
            for (int j = 0; j < 8; ++j)
                xraw[kq * 8 + j] =
                    xbase[(size_t)(d0 + kq * 32 + lq * 8 + j) * (V3 * Lq)];

        __syncthreads();
        #pragma unroll
        for (int q2 = 0; q2 < 4; ++q2) {
            int idx  = tid + q2 * 256;
            int row  = idx >> 4;
            int dloc = (idx & 15) * 4;
            float4 wv4 = *reinterpret_cast<const float4*>(
                W + (size_t)(e0 + row) * Dm + d0 + dloc);
            float wz[4] = {wv4.x, wv4.y, wv4.z, wv4.w};
            union { unsigned short u[4]; uint2 v2; } hp, lp;
            #pragma unroll
            for (int e = 0; e < 4; ++e) {
                hp.u[e] = f2bf(wz[e]);
                lp.u[e] = f2bf(wz[e] - bfbits2f(hp.u[e]));
            }
            *reinterpret_cast<uint2*>(LWh + row * WPITCH + dloc * 2) = hp.v2;
            *reinterpret_cast<uint2*>(LWl + row * WPITCH + dloc * 2) = lp.v2;
        }
        __syncthreads();

        bf16x8 xh[2], xl[2];
        #pragma unroll
        for (int kq = 0; kq < 2; ++kq)
            #pragma unroll
            for (int j = 0; j < 8; ++j) {
                float xv_ = xraw[kq * 8 + j];
                unsigned short hs = f2bf(xv_);
                unsigned short ls = f2bf(xv_ - bfbits2f(hs));
                xh[kq][j] = (short)hs;
                xl[kq][j] = (short)ls;
            }

        #pragma unroll
        for (int lt = 0; lt < 4; ++lt) {
            int erow = lt * 16 + ln15;
            #pragma unroll
            for (int kq = 0; kq < 2; ++kq) {
                bf16x8 wh = *reinterpret_cast<const bf16x8*>(
                    LWh + erow * WPITCH + kq * 64 + lq * 16);
                bf16x8 wl_ = *reinterpret_cast<const bf16x8*>(
                    LWl + erow * WPITCH + kq * 64 + lq * 16);
                acc[lt] = __builtin_amdgcn_mfma_f32_16x16x32_bf16(wh,  xh[kq], acc[lt], 0, 0, 0);
                acc[lt] = __builtin_amdgcn_mfma_f32_16x16x32_bf16(wl_, xh[kq], acc[lt], 0, 0, 0);
                acc[lt] = __builtin_amdgcn_mfma_f32_16x16x32_bf16(wh,  xl[kq], acc[lt], 0, 0, 0);
            }
        }
    }

    if (pid < 2) {
        unsigned short* Oh_ = (pid == 0) ? Qh : Kh;
        unsigned short* Ol_ = (pid == 0) ? Ql : Kl;
        size_t rowbase = ((size_t)m * Lq + l0 + wl) * 64;
        #pragma unroll
        for (int lt = 0; lt < 4; ++lt) {
            union { unsigned short u[4]; uint2 v2; } hp, lp;
            #pragma unroll
            for (int r = 0; r < 4; ++r) {
                float y = acc[lt][r];
                hp.u[r] = f2bf(y);
                lp.u[r] = f2bf(y - bfbits2f(hp.u[r]));
            }
            *reinterpret_cast<uint2*>(Oh_ + rowbase + lt * 16 + lq * 4) = hp.v2;
            *reinterpret_cast<uint2*>(Ol_ + rowbase + lt * 16 + lq * 4) = lp.v2;
        }
    } else {
        #pragma unroll
        for (int lt = 0; lt < 4; ++lt)
            #pragma unroll
            for (int r = 0; r < 4; ++r) {
                int dd = lt * 16 + lq * 4 + r;
                Vt[(((size_t)(m * 64 + dd)) << 10) + l0 + wl] = f2bf(acc[lt][r]);
            }
    }
}

// ---------------------------------------------------------------------------
// Kernel 2: MFMA fused attention, two-pass, no-max softmax.
// R7: T14 async-stage split (prefetch next tile into regs during MFMA),
//     vectorized cooperative attn write from Lp (bf16-p, R4-validated),
//     setprio around MFMA clusters.
// ---------------------------------------------------------------------------
__device__ __forceinline__ void tile_load(
    uint4* r, const unsigned short* __restrict__ src, size_t row_stride, int tid)
{
    #pragma unroll
    for (int q = 0; q < 2; ++q) {
        int u = tid + q * 256;
        int row = u >> 3, off = u & 7;
        r[q] = *reinterpret_cast<const uint4*>(src + (size_t)row * row_stride + off * 8);
    }
}
__device__ __forceinline__ void tile_write(
    const uint4* r, unsigned char* dst, int tid)
{
    #pragma unroll
    for (int q = 0; q < 2; ++q) {
        int u = tid + q * 256;
        int row = u >> 3, off = u & 7;
        *reinterpret_cast<uint4*>(dst + ((row * 128 + off * 16) ^ ((row & 7) << 4))) = r[q];
    }
}

__global__ __launch_bounds__(256) void fused_attn_kernel(
    const unsigned short* __restrict__ Qh, const unsigned short* __restrict__ Ql,
    const unsigned short* __restrict__ Kh, const unsigned short* __restrict__ Kl,
    const unsigned short* __restrict__ Vt, float* __restrict__ attn_out,
    unsigned short* __restrict__ Ot)
{
    __shared__ float4 ldsf4[2128];   // 34048 B
    unsigned char* L   = (unsigned char*)ldsf4;
    unsigned char* Lkh = L;            // 8 KiB  K-hi [s][dd]
    unsigned char* Lkl = L + 8192;     // 8 KiB  K-lo
    unsigned char* Lvt = L + 16384;    // 8 KiB  V^T [dd][s]
    unsigned char* Lp  = L + 24576;    // 8 KiB  P bf16 [l][s]
    float* rowsumW = (float*)(L + 32768);   // [4][64]
    float* invrow  = (float*)(L + 33792);   // [64]

    const int fid = blockIdx.y * gridDim.x + blockIdx.x;
    const int nid = (fid & 7) * 192 + (fid >> 3);
    const int m  = nid >> 4;
    const int l0 = (nid & 15) * 64;

    const int tid = threadIdx.x;
    const int w    = tid >> 6;
    const int ln   = tid & 63;
    const int ln15 = ln & 15;
    const int lq   = ln >> 4;
    const int sc   = w * 16;          // this wave's s-columns (QK)

    // ---- preload Q fragments (hi+lo) into registers via LDS bounce ----
    {
        uint4 rq[2];
        tile_load(rq, Qh + ((size_t)m * Lq + l0) * 64, 64, tid);
        tile_write(rq, Lkh, tid);
        tile_load(rq, Ql + ((size_t)m * Lq + l0) * 64, 64, tid);
        tile_write(rq, Lkl, tid);
    }
    __syncthreads();
    bf16x8 qfh[4][2], qfl[4][2];
    #pragma unroll
    for (int lt = 0; lt < 4; ++lt) {
        int row = lt * 16 + ln15;
        #pragma unroll
        for (int kq = 0; kq < 2; ++kq) {
            int byte = (row * 128 + kq * 64 + lq * 16) ^ ((row & 7) << 4);
            qfh[lt][kq] = *reinterpret_cast<const bf16x8*>(Lkh + byte);
            qfl[lt][kq] = *reinterpret_cast<const bf16x8*>(Lkl + byte);
        }
    }

    const size_t mbase = (size_t)m * Lq * Lq;
    const unsigned short* Khm = Kh + (size_t)m * Lq * 64;
    const unsigned short* Klm = Kl + (size_t)m * Lq * 64;
    const unsigned short* Vtm = Vt + (((size_t)m * 64) << 10);

    // ================= pass 1: row sums =================
    float lsum[4][4] = {};
    {
        uint4 rkh[2], rkl[2];
        tile_load(rkh, Khm, 64, tid);
        tile_load(rkl, Klm, 64, tid);
        for (int t = 0; t < 16; ++t) {
            __syncthreads();   // prev tile readers done (iter0: Q-frag reads done)
            tile_write(rkh, Lkh, tid);
            tile_write(rkl, Lkl, tid);
            __syncthreads();
            if (t < 15) {      // prefetch next tile while MFMAs run
                tile_load(rkh, Khm + (size_t)(t + 1) * 4096, 64, tid);
                tile_load(rkl, Klm + (size_t)(t + 1) * 4096, 64, tid);
            }
            bf16x8 bh[2], bl[2];
            #pragma unroll
            for (int kq = 0; kq < 2; ++kq) {
                int row = sc + ln15;
                int byte = (row * 128 + kq * 64 + lq * 16) ^ ((row & 7) << 4);
                bh[kq] = *reinterpret_cast<const bf16x8*>(Lkh + byte);
                bl[kq] = *reinterpret_cast<const bf16x8*>(Lkl + byte);
            }
            __builtin_amdgcn_s_setprio(1);
            f32x4 c[4];
            #pragma unroll
            for (int lt = 0; lt < 4; ++lt) {
                c[lt] = (f32x4)0.f;
                #pragma unroll
                for (int kq = 0; kq < 2; ++kq) {
                    c[lt] = __builtin_amdgcn_mfma_f32_16x16x32_bf16(qfh[lt][kq], bh[kq], c[lt], 0, 0, 0);
                    c[lt] = __builtin_amdgcn_mfma_f32_16x16x32_bf16(qfl[lt][kq], bh[kq], c[lt], 0, 0, 0);
                    c[lt] = __builtin_amdgcn_mfma_f32_16x16x32_bf16(qfh[lt][kq], bl[kq], c[lt], 0, 0, 0);
                }
            }
            __builtin_amdgcn_s_setprio(0);
            #pragma unroll
            for (int lt = 0; lt < 4; ++lt)
                #pragma unroll
                for (int r = 0; r < 4; ++r)
                    lsum[lt][r] += __expf(c[lt][r] * SCALE);
        }
    }
    #pragma unroll
    for (int lt = 0; lt < 4; ++lt)
        #pragma unroll
        for (int r = 0; r < 4; ++r) {
            float vv = lsum[lt][r];
            vv += __shfl_xor(vv, 1);
            vv += __shfl_xor(vv, 2);
            vv += __shfl_xor(vv, 4);
            vv += __shfl_xor(vv, 8);
            if (ln15 == 0) rowsumW[w * 64 + lt * 16 + lq * 4 + r] = vv;
        }
    __syncthreads();
    if (tid < 64)
        invrow[tid] = 1.0f / (rowsumW[tid] + rowsumW[64 + tid] +
                              rowsumW[128 + tid] + rowsumW[192 + tid]);
    __syncthreads();

    // ================= pass 2: attn write + PV =================
    f32x4 o[4];
    o[0] = (f32x4)0.f; o[1] = (f32x4)0.f; o[2] = (f32x4)0.f; o[3] = (f32x4)0.f;

    // cooperative attn-write geometry: thread t owns row t>>2, 16 cols
    const int arow = tid >> 2;
    const int acb  = (tid & 3) * 32;           // byte col base in Lp row
    const int aswz = (arow & 7) << 4;

    {
        uint4 rkh[2], rkl[2], rvt[2];
        tile_load(rkh, Khm, 64, tid);
        tile_load(rkl, Klm, 64, tid);
        tile_load(rvt, Vtm, 1024, tid);
        for (int t = 0; t < 16; ++t) {
            const int s0 = t * 64;
            __syncthreads();   // prev tile's LDS readers (incl. Lp coop reads) done
            tile_write(rkh, Lkh, tid);
            tile_write(rkl, Lkl, tid);
            tile_write(rvt, Lvt, tid);
            __syncthreads();
            if (t < 15) {
                tile_load(rkh, Khm + (size_t)(t + 1) * 4096, 64, tid);
                tile_load(rkl, Klm + (size_t)(t + 1) * 4096, 64, tid);
                tile_load(rvt, Vtm + (t + 1) * 64, 1024, tid);
            }
            bf16x8 bh[2], bl[2];
            #pragma unroll
            for (int kq = 0; kq < 2; ++kq) {
                int row = sc + ln15;
                int byte = (row * 128 + kq * 64 + lq * 16) ^ ((row & 7) << 4);
                bh[kq] = *reinterpret_cast<const bf16x8*>(Lkh + byte);
                bl[kq] = *reinterpret_cast<const bf16x8*>(Lkl + byte);
            }
            __builtin_amdgcn_s_setprio(1);
            f32x4 c[4];
            #pragma unroll
            for (int lt = 0; lt < 4; ++lt) {
                c[lt] = (f32x4)0.f;
                #pragma unroll
                for (int kq = 0; kq < 2; ++kq) {
                    c[lt] = __builtin_amdgcn_mfma_f32_16x16x32_bf16(qfh[lt][kq], bh[kq], c[lt], 0, 0, 0);
                    c[lt] = __builtin_amdgcn_mfma_f32_16x16x32_bf16(qfl[lt][kq], bh[kq], c[lt], 0, 0, 0);
                    c[lt] = __builtin_amdgcn_mfma_f32_16x16x32_bf16(qfh[lt][kq], bl[kq], c[lt], 0, 0, 0);
                }
            }
            __builtin_amdgcn_s_setprio(0);
            // normalized p -> Lp (bf16)
            #pragma unroll
            for (int lt = 0; lt < 4; ++lt)
                #pragma unroll
                for (int r = 0; r < 4; ++r) {
                    int l = lt * 16 + lq * 4 + r;
                    float p = __expf(c[lt][r] * SCALE) * invrow[l];
                    int byte = (l * 128 + (sc + ln15) * 2) ^ ((l & 7) << 4);
                    *reinterpret_cast<unsigned short*>(Lp + byte) = f2bf(p);
                }
            __syncthreads();   // P visible to all waves
            // PV
            __builtin_amdgcn_s_setprio(1);
            {
                int prow = w * 16 + ln15;
                #pragma unroll
                for (int kq = 0; kq < 2; ++kq) {
                    bf16x8 pa = *reinterpret_cast<const bf16x8*>(
                        Lp + ((prow * 128 + kq * 64 + lq * 16) ^ ((prow & 7) << 4)));
                    #pragma unroll
                    for (int nt = 0; nt < 4; ++nt) {
                        int vrow = nt * 16 + ln15;
                        bf16x8 vb = *reinterpret_cast<const bf16x8*>(
                            Lvt + ((vrow * 128 + kq * 64 + lq * 16) ^ ((vrow & 7) << 4)));
                        o[nt] = __builtin_amdgcn_mfma_f32_16x16x32_bf16(pa, vb, o[nt], 0, 0, 0);
                    }
                }
            }
            __builtin_amdgcn_s_setprio(0);
            // cooperative vectorized attn write (reads Lp, fully coalesced)
            {
                bf16x8 p0 = *reinterpret_cast<const bf16x8*>(
                    Lp + ((arow * 128 + acb) ^ aswz));
                bf16x8 p1 = *reinterpret_cast<const bf16x8*>(
                    Lp + ((arow * 128 + acb + 16) ^ aswz));
                float* dst = attn_out + mbase + (size_t)(l0 + arow) * Lq + s0 + (tid & 3) * 16;
                float4 f;
                f.x = bfbits2f((unsigned short)p0[0]);
                f.y = bfbits2f((unsigned short)p0[1]);
                f.z = bfbits2f((unsigned short)p0[2]);
                f.w = bfbits2f((unsigned short)p0[3]);
                *reinterpret_cast<float4*>(dst) = f;
                f.x = bfbits2f((unsigned short)p0[4]);
                f.y = bfbits2f((unsigned short)p0[5]);
                f.z = bfbits2f((unsigned short)p0[6]);
                f.w = bfbits2f((unsigned short)p0[7]);
                *reinterpret_cast<float4*>(dst + 4) = f;
                f.x = bfbits2f((unsigned short)p1[0]);
                f.y = bfbits2f((unsigned short)p1[1]);
                f.z = bfbits2f((unsigned short)p1[2]);
                f.w = bfbits2f((unsigned short)p1[3]);
                *reinterpret_cast<float4*>(dst + 8) = f;
                f.x = bfbits2f((unsigned short)p1[4]);
                f.y = bfbits2f((unsigned short)p1[5]);
                f.z = bfbits2f((unsigned short)p1[6]);
                f.w = bfbits2f((unsigned short)p1[7]);
                *reinterpret_cast<float4*>(dst + 12) = f;
            }
        }
    }

    // ---- O epilogue: direct stores, NATURAL [m][l][dd] ----
    #pragma unroll
    for (int nt = 0; nt < 4; ++nt) {
        int dd = nt * 16 + ln15;
        #pragma unroll
        for (int r = 0; r < 4; ++r) {
            int l = w * 16 + lq * 4 + r;
            Ot[((size_t)m * Lq + l0 + l) * 64 + dd] = f2bf(o[nt][r]);
        }
    }
}

// ---------------------------------------------------------------------------
// Kernel 3: MFMA output projection (unchanged from R6).
// ---------------------------------------------------------------------------
__global__ __launch_bounds__(256, 4) void oproj_kernel(
    const float* __restrict__ Wo, const unsigned short* __restrict__ Ot,
    float* __restrict__ out)
{
    __shared__ unsigned char Wlds[2 * 64 * WPITCH];
    unsigned char* LWh = Wlds;
    unsigned char* LWl = Wlds + 64 * WPITCH;

    const int fid = (blockIdx.z * gridDim.y + blockIdx.y) * gridDim.x + blockIdx.x;
    const int nid = (fid & 7) * 192 + (fid >> 3);
    const int x_  = nid & 15;
    const int y_  = (nid >> 4) & 7;
    const int pl  = nid >> 7;
    const int b   = pl / V3;
    const int v   = pl % V3;

    const int l0 = x_ * 64;
    const int e0 = y_ * 64;

    const int tid  = threadIdx.x;
    const int w    = tid >> 6;
    const int ln   = tid & 63;
    const int ln15 = ln & 15;
    const int lq   = ln >> 4;
    const int wl   = w * 16 + ln15;

    f32x4 acc[4];
    #pragma unroll
    for (int i = 0; i < 4; ++i) acc[i] = (f32x4)0.f;

    for (int h = 0; h < Hh; ++h) {
        const int m = (b * Hh + h) * V3 + v;

        size_t obase = ((size_t)m * Lq + l0 + wl) * 64;
        bf16x8 ob0 = *reinterpret_cast<const bf16x8*>(Ot + obase + lq * 8);
        bf16x8 ob1 = *reinterpret_cast<const bf16x8*>(Ot + obase + 32 + lq * 8);

        __syncthreads();
        #pragma unroll
        for (int q2 = 0; q2 < 4; ++q2) {
            int idx  = tid + q2 * 256;
            int row  = idx >> 4;
            int dloc = (idx & 15) * 4;
            float4 wv4 = *reinterpret_cast<const float4*>(
                Wo + (size_t)(e0 + row) * Dm + h * 64 + dloc);
            float wz[4] = {wv4.x, wv4.y, wv4.z, wv4.w};
            union { unsigned short u[4]; uint2 v2; } hp, lp;
            #pragma unroll
            for (int e = 0; e < 4; ++e) {
                hp.u[e] = f2bf(wz[e]);
                lp.u[e] = f2bf(wz[e] - bfbits2f(hp.u[e]));
            }
            *reinterpret_cast<uint2*>(LWh + row * WPITCH + dloc * 2) = hp.v2;
            *reinterpret_cast<uint2*>(LWl + row * WPITCH + dloc * 2) = lp.v2;
        }
        __syncthreads();

        #pragma unroll
        for (int lt = 0; lt < 4; ++lt) {
            int erow = lt * 16 + ln15;
            #pragma unroll
            for (int kq = 0; kq < 2; ++kq) {
                bf16x8 wh = *reinterpret_cast<const bf16x8*>(
                    LWh + erow * WPITCH + kq * 64 + lq * 16);
                bf16x8 wl_ = *reinterpret_cast<const bf16x8*>(
                    LWl + erow * WPITCH + kq * 64 + lq * 16);
                bf16x8 ob = kq ? ob1 : ob0;
                acc[lt] = __builtin_amdgcn_mfma_f32_16x16x32_bf16(wh,  ob, acc[lt], 0, 0, 0);
                acc[lt] = __builtin_amdgcn_mfma_f32_16x16x32_bf16(wl_, ob, acc[lt], 0, 0, 0);
            }
        }
    }

    #pragma unroll
    for (int lt = 0; lt < 4; ++lt)
        #pragma unroll
        for (int r = 0; r < 4; ++r) {
            int e = e0 + lt * 16 + lq * 4 + r;
            out[((size_t)(b * Dm + e) * V3 + v) * Lq + l0 + wl] = acc[lt][r];
        }
}

// ---------------------------------------------------------------------------
extern "C" void kernel_launch(void* const* d_in, const int* in_sizes, int n_in,
                              void* d_out, int out_size, void* d_ws, size_t ws_size,
                              hipStream_t stream)
{
    const float* q  = (const float*)d_in[0];
    const float* k  = (const float*)d_in[1];
    const float* vv = (const float*)d_in[2];
    const float* Wq = (const float*)d_in[3];
    const float* Wk = (const float*)d_in[4];
    const float* Wv = (const float*)d_in[5];
    const float* Wo = (const float*)d_in[6];

    float* out      = (float*)d_out;
    float* attn_out = out + (size_t)Bn * Dm * V3 * Lq;   // 6,291,456 elems in

    // workspace layout (bytes), each buffer 12,582,912 B (bf16 [96][1024][64]):
    //   Qh 0 | Ql 12582912 | Kh 25165824 | Kl 37748736 | Vt 50331648 | Ot 62914560
    char* w = (char*)d_ws;
    unsigned short* Qh = (unsigned short*)(w);
    unsigned short* Ql = (unsigned short*)(w + 12582912);
    unsigned short* Kh = (unsigned short*)(w + 25165824);
    unsigned short* Kl = (unsigned short*)(w + 37748736);
    unsigned short* Vt = (unsigned short*)(w + 50331648);
    unsigned short* Ot = (unsigned short*)(w + 62914560);

    dim3 b256(256);

    proj_all_kernel<<<dim3(16, 8, 36), b256, 0, stream>>>(
        q, k, vv, Wq, Wk, Wv, Qh, Ql, Kh, Kl, Vt);

    fused_attn_kernel<<<dim3(16, NM), b256, 0, stream>>>(
        Qh, Ql, Kh, Kl, Vt, attn_out, Ot);

    oproj_kernel<<<dim3(16, 8, 12), b256, 0, stream>>>(Wo, Ot, out);
}

// Round 8
// 721.742 us; speedup vs baseline: 1.1994x; 1.1994x over previous
//
#include <hip/hip_runtime.h>
#include <hip/hip_bf16.h>

typedef __hip_bfloat16 bf16;
using bf16x8 = __attribute__((ext_vector_type(8))) short;   // MFMA A/B frag (4 VGPR)
using f32x4  = __attribute__((ext_vector_type(4))) float;   // MFMA C/D frag

#define Bn 4
#define Dm 512
#define Hh 8
#define V3 3
#define Lq 1024
#define NM (Bn*Hh*V3)   // 96 attention maps

#define WPITCH 144      // bf16 LDS row pitch in BYTES: 16B-aligned, bank-skewed

__device__ __forceinline__ unsigned short f2bf(float x) {
    bf16 h = __float2bfloat16(x);
    return *reinterpret_cast<unsigned short*>(&h);
}
__device__ __forceinline__ float bfbits2f(unsigned short u) {
    return __uint_as_float((unsigned)u << 16);
}

constexpr float SCALE = 0.57735026919f; // 1/sqrt(3)

// ---------------------------------------------------------------------------
// Kernel 1: ALL THREE projections via MFMA (split-bf16 3-term compensation).
// (unchanged from R6)
// ---------------------------------------------------------------------------
__global__ __launch_bounds__(256, 4) void proj_all_kernel(
    const float* __restrict__ xq, const float* __restrict__ xk,
    const float* __restrict__ xv,
    const float* __restrict__ Wq, const float* __restrict__ Wk,
    const float* __restrict__ Wv,
    unsigned short* __restrict__ Qh, unsigned short* __restrict__ Ql,
    unsigned short* __restrict__ Kh, unsigned short* __restrict__ Kl,
    unsigned short* __restrict__ Vt)
{
    __shared__ unsigned char Wlds[2 * 64 * WPITCH];   // Wh | Wl, 18432 B
    unsigned char* LWh = Wlds;
    unsigned char* LWl = Wlds + 64 * WPITCH;

    const int fid = (blockIdx.z * gridDim.y + blockIdx.y) * gridDim.x + blockIdx.x;
    const int nid = (fid & 7) * 576 + (fid >> 3);
    const int x_  = nid & 15;          // l-block (16)
    const int y_  = (nid >> 4) & 7;    // e-block (8) == head
    const int zz  = nid >> 7;          // 0..35
    const int pid = zz / 12;           // 0=Q 1=K 2=V
    const int pl  = zz % 12;
    const int b   = pl / V3;
    const int v   = pl % V3;

    const float* xsrc = (pid == 0) ? xq : (pid == 1) ? xk : xv;
    const float* W    = (pid == 0) ? Wq : (pid == 1) ? Wk : Wv;

    const int l0 = x_ * 64;
    const int e0 = y_ * 64;
    const int m  = (b * Hh + y_) * V3 + v;

    const int tid  = threadIdx.x;
    const int w    = tid >> 6;
    const int ln   = tid & 63;
    const int ln15 = ln & 15;
    const int lq   = ln >> 4;
    const int wl   = w * 16 + ln15;    // this lane's block-local l

    const float* xbase = xsrc + (size_t)b * Dm * V3 * Lq + (size_t)v * Lq + l0 + wl;

    f32x4 acc[4];
    #pragma unroll
    for (int i = 0; i < 4; ++i) acc[i] = (f32x4)0.f;

    for (int ph = 0; ph < 8; ++ph) {
        const int d0 = ph * 64;

        float xraw[16];
        #pragma unroll
        for (int kq = 0; kq < 2; ++kq)
            #pragma unroll
            for (int j = 0; j < 8; ++j)
                xraw[kq * 8 + j] =
                    xbase[(size_t)(d0 + kq * 32 + lq * 8 + j) * (V3 * Lq)];

        __syncthreads();
        #pragma unroll
        for (int q2 = 0; q2 < 4; ++q2) {
            int idx  = tid + q2 * 256;
            int row  = idx >> 4;
            int dloc = (idx & 15) * 4;
            float4 wv4 = *reinterpret_cast<const float4*>(
                W + (size_t)(e0 + row) * Dm + d0 + dloc);
            float wz[4] = {wv4.x, wv4.y, wv4.z, wv4.w};
            union { unsigned short u[4]; uint2 v2; } hp, lp;
            #pragma unroll
            for (int e = 0; e < 4; ++e) {
                hp.u[e] = f2bf(wz[e]);
                lp.u[e] = f2bf(wz[e] - bfbits2f(hp.u[e]));
            }
            *reinterpret_cast<uint2*>(LWh + row * WPITCH + dloc * 2) = hp.v2;
            *reinterpret_cast<uint2*>(LWl + row * WPITCH + dloc * 2) = lp.v2;
        }
        __syncthreads();

        bf16x8 xh[2], xl[2];
        #pragma unroll
        for (int kq = 0; kq < 2; ++kq)
            #pragma unroll
            for (int j = 0; j < 8; ++j) {
                float xv_ = xraw[kq * 8 + j];
                unsigned short hs = f2bf(xv_);
                unsigned short ls = f2bf(xv_ - bfbits2f(hs));
                xh[kq][j] = (short)hs;
                xl[kq][j] = (short)ls;
            }

        #pragma unroll
        for (int lt = 0; lt < 4; ++lt) {
            int erow = lt * 16 + ln15;
            #pragma unroll
            for (int kq = 0; kq < 2; ++kq) {
                bf16x8 wh = *reinterpret_cast<const bf16x8*>(
                    LWh + erow * WPITCH + kq * 64 + lq * 16);
                bf16x8 wl_ = *reinterpret_cast<const bf16x8*>(
                    LWl + erow * WPITCH + kq * 64 + lq * 16);
                acc[lt] = __builtin_amdgcn_mfma_f32_16x16x32_bf16(wh,  xh[kq], acc[lt], 0, 0, 0);
                acc[lt] = __builtin_amdgcn_mfma_f32_16x16x32_bf16(wl_, xh[kq], acc[lt], 0, 0, 0);
                acc[lt] = __builtin_amdgcn_mfma_f32_16x16x32_bf16(wh,  xl[kq], acc[lt], 0, 0, 0);
            }
        }
    }

    if (pid < 2) {
        unsigned short* Oh_ = (pid == 0) ? Qh : Kh;
        unsigned short* Ol_ = (pid == 0) ? Ql : Kl;
        size_t rowbase = ((size_t)m * Lq + l0 + wl) * 64;
        #pragma unroll
        for (int lt = 0; lt < 4; ++lt) {
            union { unsigned short u[4]; uint2 v2; } hp, lp;
            #pragma unroll
            for (int r = 0; r < 4; ++r) {
                float y = acc[lt][r];
                hp.u[r] = f2bf(y);
                lp.u[r] = f2bf(y - bfbits2f(hp.u[r]));
            }
            *reinterpret_cast<uint2*>(Oh_ + rowbase + lt * 16 + lq * 4) = hp.v2;
            *reinterpret_cast<uint2*>(Ol_ + rowbase + lt * 16 + lq * 4) = lp.v2;
        }
    } else {
        #pragma unroll
        for (int lt = 0; lt < 4; ++lt)
            #pragma unroll
            for (int r = 0; r < 4; ++r) {
                int dd = lt * 16 + lq * 4 + r;
                Vt[(((size_t)(m * 64 + dd)) << 10) + l0 + wl] = f2bf(acc[lt][r]);
            }
    }
}

// ---------------------------------------------------------------------------
// Kernel 2: MFMA fused attention, two-pass, no-max softmax.
// R8 = R6 structure (stage->barrier->compute->barrier; no reg-prefetch, no
// setprio) + ONE change: cooperative vectorized attn write from Lp
// (4 coalesced float4 stores/lane/tile instead of 16 scalar dword stores).
// ---------------------------------------------------------------------------
__device__ __forceinline__ void stage_tile64(
    unsigned char* dst, const unsigned short* __restrict__ src,
    size_t row_stride, int tid)
{
    #pragma unroll
    for (int q = 0; q < 2; ++q) {
        int u = tid + q * 256;              // 512 units of 16B
        int row = u >> 3, off = u & 7;
        uint4 d = *reinterpret_cast<const uint4*>(src + (size_t)row * row_stride + off * 8);
        *reinterpret_cast<uint4*>(dst + ((row * 128 + off * 16) ^ ((row & 7) << 4))) = d;
    }
}

__global__ __launch_bounds__(256) void fused_attn_kernel(
    const unsigned short* __restrict__ Qh, const unsigned short* __restrict__ Ql,
    const unsigned short* __restrict__ Kh, const unsigned short* __restrict__ Kl,
    const unsigned short* __restrict__ Vt, float* __restrict__ attn_out,
    unsigned short* __restrict__ Ot)
{
    __shared__ float4 ldsf4[2128];   // 34048 B
    unsigned char* L   = (unsigned char*)ldsf4;
    unsigned char* Lkh = L;            // 8 KiB  K-hi [s][dd]
    unsigned char* Lkl = L + 8192;     // 8 KiB  K-lo
    unsigned char* Lvt = L + 16384;    // 8 KiB  V^T [dd][s]
    unsigned char* Lp  = L + 24576;    // 8 KiB  P bf16 [l][s]
    float* rowsumW = (float*)(L + 32768);   // [4][64]
    float* invrow  = (float*)(L + 33792);   // [64]

    const int fid = blockIdx.y * gridDim.x + blockIdx.x;
    const int nid = (fid & 7) * 192 + (fid >> 3);
    const int m  = nid >> 4;
    const int l0 = (nid & 15) * 64;

    const int tid = threadIdx.x;
    const int w    = tid >> 6;
    const int ln   = tid & 63;
    const int ln15 = ln & 15;
    const int lq   = ln >> 4;
    const int sc   = w * 16;          // this wave's s-columns (QK)

    // ---- preload Q fragments (hi+lo) into registers via LDS bounce ----
    stage_tile64(Lkh, Qh + ((size_t)m * Lq + l0) * 64, 64, tid);
    stage_tile64(Lkl, Ql + ((size_t)m * Lq + l0) * 64, 64, tid);
    __syncthreads();
    bf16x8 qfh[4][2], qfl[4][2];
    #pragma unroll
    for (int lt = 0; lt < 4; ++lt) {
        int row = lt * 16 + ln15;
        #pragma unroll
        for (int kq = 0; kq < 2; ++kq) {
            int byte = (row * 128 + kq * 64 + lq * 16) ^ ((row & 7) << 4);
            qfh[lt][kq] = *reinterpret_cast<const bf16x8*>(Lkh + byte);
            qfl[lt][kq] = *reinterpret_cast<const bf16x8*>(Lkl + byte);
        }
    }
    __syncthreads();

    const size_t mbase = (size_t)m * Lq * Lq;
    const unsigned short* Khm = Kh + (size_t)m * Lq * 64;
    const unsigned short* Klm = Kl + (size_t)m * Lq * 64;
    const unsigned short* Vtm = Vt + (((size_t)m * 64) << 10);

    // ================= pass 1: row sums =================
    float lsum[4][4] = {};
    for (int s0 = 0; s0 < Lq; s0 += 64) {
        stage_tile64(Lkh, Khm + (size_t)s0 * 64, 64, tid);
        stage_tile64(Lkl, Klm + (size_t)s0 * 64, 64, tid);
        __syncthreads();
        bf16x8 bh[2], bl[2];
        #pragma unroll
        for (int kq = 0; kq < 2; ++kq) {
            int row = sc + ln15;
            int byte = (row * 128 + kq * 64 + lq * 16) ^ ((row & 7) << 4);
            bh[kq] = *reinterpret_cast<const bf16x8*>(Lkh + byte);
            bl[kq] = *reinterpret_cast<const bf16x8*>(Lkl + byte);
        }
        #pragma unroll
        for (int lt = 0; lt < 4; ++lt) {
            f32x4 c = (f32x4)0.f;
            #pragma unroll
            for (int kq = 0; kq < 2; ++kq) {
                c = __builtin_amdgcn_mfma_f32_16x16x32_bf16(qfh[lt][kq], bh[kq], c, 0, 0, 0);
                c = __builtin_amdgcn_mfma_f32_16x16x32_bf16(qfl[lt][kq], bh[kq], c, 0, 0, 0);
                c = __builtin_amdgcn_mfma_f32_16x16x32_bf16(qfh[lt][kq], bl[kq], c, 0, 0, 0);
            }
            #pragma unroll
            for (int r = 0; r < 4; ++r)
                lsum[lt][r] += __expf(c[r] * SCALE);
        }
        __syncthreads();
    }
    #pragma unroll
    for (int lt = 0; lt < 4; ++lt)
        #pragma unroll
        for (int r = 0; r < 4; ++r) {
            float vv = lsum[lt][r];
            vv += __shfl_xor(vv, 1);
            vv += __shfl_xor(vv, 2);
            vv += __shfl_xor(vv, 4);
            vv += __shfl_xor(vv, 8);
            if (ln15 == 0) rowsumW[w * 64 + lt * 16 + lq * 4 + r] = vv;
        }
    __syncthreads();
    if (tid < 64)
        invrow[tid] = 1.0f / (rowsumW[tid] + rowsumW[64 + tid] +
                              rowsumW[128 + tid] + rowsumW[192 + tid]);
    __syncthreads();

    // ================= pass 2: attn write + PV =================
    f32x4 o[4];
    o[0] = (f32x4)0.f; o[1] = (f32x4)0.f; o[2] = (f32x4)0.f; o[3] = (f32x4)0.f;

    // cooperative attn-write geometry: thread t owns row t>>2, 16 cols
    const int arow = tid >> 2;
    const int acb  = (tid & 3) * 32;           // byte col base in Lp row
    const int aswz = (arow & 7) << 4;

    for (int s0 = 0; s0 < Lq; s0 += 64) {
        stage_tile64(Lkh, Khm + (size_t)s0 * 64, 64, tid);
        stage_tile64(Lkl, Klm + (size_t)s0 * 64, 64, tid);
        stage_tile64(Lvt, Vtm + s0, 1024, tid);
        __syncthreads();
        bf16x8 bh[2], bl[2];
        #pragma unroll
        for (int kq = 0; kq < 2; ++kq) {
            int row = sc + ln15;
            int byte = (row * 128 + kq * 64 + lq * 16) ^ ((row & 7) << 4);
            bh[kq] = *reinterpret_cast<const bf16x8*>(Lkh + byte);
            bl[kq] = *reinterpret_cast<const bf16x8*>(Lkl + byte);
        }
        #pragma unroll
        for (int lt = 0; lt < 4; ++lt) {
            f32x4 c = (f32x4)0.f;
            #pragma unroll
            for (int kq = 0; kq < 2; ++kq) {
                c = __builtin_amdgcn_mfma_f32_16x16x32_bf16(qfh[lt][kq], bh[kq], c, 0, 0, 0);
                c = __builtin_amdgcn_mfma_f32_16x16x32_bf16(qfl[lt][kq], bh[kq], c, 0, 0, 0);
                c = __builtin_amdgcn_mfma_f32_16x16x32_bf16(qfh[lt][kq], bl[kq], c, 0, 0, 0);
            }
            #pragma unroll
            for (int r = 0; r < 4; ++r) {
                int l = lt * 16 + lq * 4 + r;
                float p = __expf(c[r] * SCALE) * invrow[l];
                int byte = (l * 128 + (sc + ln15) * 2) ^ ((l & 7) << 4);
                *reinterpret_cast<unsigned short*>(Lp + byte) = f2bf(p);
            }
        }
        __syncthreads();   // P visible to all waves
        // PV
        {
            int prow = w * 16 + ln15;
            #pragma unroll
            for (int kq = 0; kq < 2; ++kq) {
                bf16x8 pa = *reinterpret_cast<const bf16x8*>(
                    Lp + ((prow * 128 + kq * 64 + lq * 16) ^ ((prow & 7) << 4)));
                #pragma unroll
                for (int nt = 0; nt < 4; ++nt) {
                    int vrow = nt * 16 + ln15;
                    bf16x8 vb = *reinterpret_cast<const bf16x8*>(
                        Lvt + ((vrow * 128 + kq * 64 + lq * 16) ^ ((vrow & 7) << 4)));
                    o[nt] = __builtin_amdgcn_mfma_f32_16x16x32_bf16(pa, vb, o[nt], 0, 0, 0);
                }
            }
        }
        // cooperative vectorized attn write (reads Lp, fully coalesced)
        {
            bf16x8 p0 = *reinterpret_cast<const bf16x8*>(
                Lp + ((arow * 128 + acb) ^ aswz));
            bf16x8 p1 = *reinterpret_cast<const bf16x8*>(
                Lp + ((arow * 128 + acb + 16) ^ aswz));
            float* dst = attn_out + mbase + (size_t)(l0 + arow) * Lq + s0 + (tid & 3) * 16;
            float4 f;
            f.x = bfbits2f((unsigned short)p0[0]);
            f.y = bfbits2f((unsigned short)p0[1]);
            f.z = bfbits2f((unsigned short)p0[2]);
            f.w = bfbits2f((unsigned short)p0[3]);
            *reinterpret_cast<float4*>(dst) = f;
            f.x = bfbits2f((unsigned short)p0[4]);
            f.y = bfbits2f((unsigned short)p0[5]);
            f.z = bfbits2f((unsigned short)p0[6]);
            f.w = bfbits2f((unsigned short)p0[7]);
            *reinterpret_cast<float4*>(dst + 4) = f;
            f.x = bfbits2f((unsigned short)p1[0]);
            f.y = bfbits2f((unsigned short)p1[1]);
            f.z = bfbits2f((unsigned short)p1[2]);
            f.w = bfbits2f((unsigned short)p1[3]);
            *reinterpret_cast<float4*>(dst + 8) = f;
            f.x = bfbits2f((unsigned short)p1[4]);
            f.y = bfbits2f((unsigned short)p1[5]);
            f.z = bfbits2f((unsigned short)p1[6]);
            f.w = bfbits2f((unsigned short)p1[7]);
            *reinterpret_cast<float4*>(dst + 12) = f;
        }
        __syncthreads();   // Lvt/Lp readers done; safe to restage
    }

    // ---- O epilogue: direct stores, NATURAL [m][l][dd] ----
    #pragma unroll
    for (int nt = 0; nt < 4; ++nt) {
        int dd = nt * 16 + ln15;
        #pragma unroll
        for (int r = 0; r < 4; ++r) {
            int l = w * 16 + lq * 4 + r;
            Ot[((size_t)m * Lq + l0 + l) * 64 + dd] = f2bf(o[nt][r]);
        }
    }
}

// ---------------------------------------------------------------------------
// Kernel 3: MFMA output projection (unchanged from R6).
// ---------------------------------------------------------------------------
__global__ __launch_bounds__(256, 4) void oproj_kernel(
    const float* __restrict__ Wo, const unsigned short* __restrict__ Ot,
    float* __restrict__ out)
{
    __shared__ unsigned char Wlds[2 * 64 * WPITCH];
    unsigned char* LWh = Wlds;
    unsigned char* LWl = Wlds + 64 * WPITCH;

    const int fid = (blockIdx.z * gridDim.y + blockIdx.y) * gridDim.x + blockIdx.x;
    const int nid = (fid & 7) * 192 + (fid >> 3);
    const int x_  = nid & 15;
    const int y_  = (nid >> 4) & 7;
    const int pl  = nid >> 7;
    const int b   = pl / V3;
    const int v   = pl % V3;

    const int l0 = x_ * 64;
    const int e0 = y_ * 64;

    const int tid  = threadIdx.x;
    const int w    = tid >> 6;
    const int ln   = tid & 63;
    const int ln15 = ln & 15;
    const int lq   = ln >> 4;
    const int wl   = w * 16 + ln15;

    f32x4 acc[4];
    #pragma unroll
    for (int i = 0; i < 4; ++i) acc[i] = (f32x4)0.f;

    for (int h = 0; h < Hh; ++h) {
        const int m = (b * Hh + h) * V3 + v;

        size_t obase = ((size_t)m * Lq + l0 + wl) * 64;
        bf16x8 ob0 = *reinterpret_cast<const bf16x8*>(Ot + obase + lq * 8);
        bf16x8 ob1 = *reinterpret_cast<const bf16x8*>(Ot + obase + 32 + lq * 8);

        __syncthreads();
        #pragma unroll
        for (int q2 = 0; q2 < 4; ++q2) {
            int idx  = tid + q2 * 256;
            int row  = idx >> 4;
            int dloc = (idx & 15) * 4;
            float4 wv4 = *reinterpret_cast<const float4*>(
                Wo + (size_t)(e0 + row) * Dm + h * 64 + dloc);
            float wz[4] = {wv4.x, wv4.y, wv4.z, wv4.w};
            union { unsigned short u[4]; uint2 v2; } hp, lp;
            #pragma unroll
            for (int e = 0; e < 4; ++e) {
                hp.u[e] = f2bf(wz[e]);
                lp.u[e] = f2bf(wz[e] - bfbits2f(hp.u[e]));
            }
            *reinterpret_cast<uint2*>(LWh + row * WPITCH + dloc * 2) = hp.v2;
            *reinterpret_cast<uint2*>(LWl + row * WPITCH + dloc * 2) = lp.v2;
        }
        __syncthreads();

        #pragma unroll
        for (int lt = 0; lt < 4; ++lt) {
            int erow = lt * 16 + ln15;
            #pragma unroll
            for (int kq = 0; kq < 2; ++kq) {
                bf16x8 wh = *reinterpret_cast<const bf16x8*>(
                    LWh + erow * WPITCH + kq * 64 + lq * 16);
                bf16x8 wl_ = *reinterpret_cast<const bf16x8*>(
                    LWl + erow * WPITCH + kq * 64 + lq * 16);
                bf16x8 ob = kq ? ob1 : ob0;
                acc[lt] = __builtin_amdgcn_mfma_f32_16x16x32_bf16(wh,  ob, acc[lt], 0, 0, 0);
                acc[lt] = __builtin_amdgcn_mfma_f32_16x16x32_bf16(wl_, ob, acc[lt], 0, 0, 0);
            }
        }
    }

    #pragma unroll
    for (int lt = 0; lt < 4; ++lt)
        #pragma unroll
        for (int r = 0; r < 4; ++r) {
            int e = e0 + lt * 16 + lq * 4 + r;
            out[((size_t)(b * Dm + e) * V3 + v) * Lq + l0 + wl] = acc[lt][r];
        }
}

// ---------------------------------------------------------------------------
extern "C" void kernel_launch(void* const* d_in, const int* in_sizes, int n_in,
                              void* d_out, int out_size, void* d_ws, size_t ws_size,
                              hipStream_t stream)
{
    const float* q  = (const float*)d_in[0];
    const float* k  = (const float*)d_in[1];
    const float* vv = (const float*)d_in[2];
    const float* Wq = (const float*)d_in[3];
    const float* Wk = (const float*)d_in[4];
    const float* Wv = (const float*)d_in[5];
    const float* Wo = (const float*)d_in[6];

    float* out      = (float*)d_out;
    float* attn_out = out + (size_t)Bn * Dm * V3 * Lq;   // 6,291,456 elems in

    // workspace layout (bytes), each buffer 12,582,912 B (bf16 [96][1024][64]):
    //   Qh 0 | Ql 12582912 | Kh 25165824 | Kl 37748736 | Vt 50331648 | Ot 62914560
    char* w = (char*)d_ws;
    unsigned short* Qh = (unsigned short*)(w);
    unsigned short* Ql = (unsigned short*)(w + 12582912);
    unsigned short* Kh = (unsigned short*)(w + 25165824);
    unsigned short* Kl = (unsigned short*)(w + 37748736);
    unsigned short* Vt = (unsigned short*)(w + 50331648);
    unsigned short* Ot = (unsigned short*)(w + 62914560);

    dim3 b256(256);

    proj_all_kernel<<<dim3(16, 8, 36), b256, 0, stream>>>(
        q, k, vv, Wq, Wk, Wv, Qh, Ql, Kh, Kl, Vt);

    fused_attn_kernel<<<dim3(16, NM), b256, 0, stream>>>(
        Qh, Ql, Kh, Kl, Vt, attn_out, Ot);

    oproj_kernel<<<dim3(16, 8, 12), b256, 0, stream>>>(Wo, Ot, out);
}